// Round 12
// baseline (976.260 us; speedup 1.0000x reference)
//
#include <hip/hip_runtime.h>
#include <hip/hip_bf16.h>
#include <stdint.h>

// ---------------------------------------------------------------------------
// out = net(x) + P(net(P(x))), P = swap (W,X)<->(Y,Z).  Equivariance:
// P(net(P(x);W)) = net(x; P_w(W)) -> one network, 2 weight branches.
//
// Round 12: conv2 v6 = r11's proven overlap engine (256-thr/4-wave blocks,
// 780-granule dbuf slab, hoisted staging) with the r6-proven 32x32 z-shift
// MFMA math: 12 reads + 12 MFMA per wave-phase (half the LDS bytes/FLOP),
// B (Wp2T) JIT from global to regs.  Wave owns 24 anchors, M padded to 32
// (8 clamped junk rows, store-skipped).  conv3: B taps global->regs
// (wave-phase LDS reads 36->27).  conv1/prep/halo/schedule unchanged.
// ---------------------------------------------------------------------------

#define S   24
#define S2  576
#define S3  13824
#define S4  331776

typedef __attribute__((ext_vector_type(8)))  short bf16x8;
typedef __attribute__((ext_vector_type(4)))  float f32x4;
typedef __attribute__((ext_vector_type(16))) float f32x16;
typedef __attribute__((ext_vector_type(4)))  int   i32x4;

__device__ __forceinline__ uint32_t f2bf(float f) {            // RNE f32->bf16
    uint32_t u = __float_as_uint(f);
    return (u + 0x7FFFu + ((u >> 16) & 1u)) >> 16;
}
__device__ __forceinline__ int permtap(int t) {                // (kw,kx,ky,kz)->(ky,kz,kw,kx)
    int kw = t / 27, kx = (t / 9) % 3, ky = (t / 3) % 3, kz = t % 3;
    return ky * 27 + kz * 9 + kw * 3 + kx;
}

// ---------------- workspace map (bytes) ----------------
// Wp1  f32  [2br][81][16co]           @ 0      10368
// Wp3c bf16 [2br][81][16ci]           @ 10368  5184
// Wp2T bf16 [2br][9ph][12a][64l][8j]  @ 16384  221184  (ends 237568)
#define WP1_OFF    0
#define WP3C_OFF   10368
#define WP2T_OFF   16384
#define BUF_OFF    262144
#define Y1P_PER_BR 12460032ull
#define Y2P_IN     24920064ull
#define PER_N      49840128ull
#define WS_NEED    (BUF_OFF + PER_N)

// ---------------- prep: pack weights (parallel, r6-proven) ----------------
__global__ void prep_weights(const float* __restrict__ w1, const float* __restrict__ w2,
                             const float* __restrict__ w3,
                             float* __restrict__ Wp1, ushort* __restrict__ Wp3c,
                             ushort* __restrict__ Wp2T) {
    const int bid = blockIdx.x, tid = threadIdx.x;
    if (bid < 432) {
        int i = bid * 256 + tid;                    // 110592 Wp2T elements
        int j = i & 7, lane = (i >> 3) & 63, rest = i >> 9;   // rest=(br*9+ph)*12+a
        int a = rest % 12, ph = (rest / 12) % 9, br = rest / 108;
        int col = lane & 31, co = col & 15, s = col >> 4;
        int ci = (lane >> 5) * 8 + j;
        int dy = a >> 2, dzA = a & 3, dz = dzA - s;
        ushort v = 0;
        if (dz >= 0 && dz <= 2) {
            int dw = ph / 3, dx = ph % 3;
            int t = dw * 27 + dx * 9 + dy * 3 + dz;
            int ts = br ? permtap(t) : t;
            v = (ushort)f2bf(w2[(co * 16 + ci) * 81 + ts]);
        }
        Wp2T[i] = v;
    } else {
        int i = (bid - 432) * 256 + tid;
        if (i < 2592) {
            int ci = i & 15, t = (i >> 4) % 81, br = i / 1296;
            int ts = br ? permtap(t) : t;
            Wp1[i]  = w1[ci * 81 + ts];
            Wp3c[i] = (ushort)f2bf(w3[ci * 81 + ts]);
        }
    }
}

// ---------------- halo zero: (y,z) borders of y1p (2br) + y2p per buffer ---
__global__ __launch_bounds__(256) void halo_zero(char* __restrict__ bufbase) {
    const int tid = threadIdx.x;
    const int pb = blockIdx.x % 576, nb = blockIdx.x / 576;
    char* buf = bufbase + (size_t)nb * PER_N;
    for (int i = tid; i < 800; i += 256) {
        int cell, part, sect;
        if (i < 400) { sect = i / 200; cell = (i % 200) >> 1; part = i & 1; }
        else         { sect = 2;       cell = (i - 400) >> 2; part = i & 3; }
        int cy, cz;
        if (cell < 26)      { cy = 0;  cz = cell; }
        else if (cell < 52) { cy = 25; cz = cell - 26; }
        else if (cell < 76) { cy = cell - 51; cz = 0; }
        else                { cy = cell - 75; cz = 25; }
        size_t rec = (size_t)pb * 676 + cy * 26 + cz;
        char* dst;
        if (sect < 2) dst = buf + (size_t)sect * Y1P_PER_BR + rec * 32 + part * 16;
        else          dst = buf + Y2P_IN + rec * 64 + part * 16;
        *(uint4*)dst = make_uint4(0u, 0u, 0u, 0u);
    }
}

// ---------------- conv1: x (1ch f32) -> y1p (16ch bf16, padded), BOTH br ----
__global__ __launch_bounds__(576) void conv1_plane2(
    const float* __restrict__ x_c, const float* __restrict__ Wp1g,
    const float* __restrict__ b1, char* __restrict__ bufbase) {
    __shared__ float xl[9 * 676];
    const int tid = threadIdx.x;
    const int nl = blockIdx.x / 576, pb = blockIdx.x % 576;
    const float* xn = x_c + (size_t)nl * S4;
    uint32_t* y1p0 = (uint32_t*)(bufbase + (size_t)nl * PER_N);
    const int w = pb / 24, xx = pb % 24;
    for (int g = tid; g < 6084; g += 576) {
        int wi = g / 2028, r1 = g - wi * 2028;
        int xi = r1 / 676, r2 = r1 - xi * 676;
        int yp = r2 / 26, zp = r2 - yp * 26;
        int ws_ = w + wi - 1, xs = xx + xi - 1, ys = yp - 1, zs = zp - 1;
        float v = 0.f;
        if ((unsigned)ws_ < 24u && (unsigned)xs < 24u && (unsigned)ys < 24u && (unsigned)zs < 24u)
            v = xn[((ws_ * 24 + xs) * 24 + ys) * 24 + zs];
        xl[g] = v;
    }
    __syncthreads();
    const int yy = tid / 24, zz = tid - (tid / 24) * 24;
    float a0[16], a1[16];
#pragma unroll
    for (int c = 0; c < 16; ++c) { a0[c] = 0.f; a1[c] = 0.f; }
#pragma unroll 1
    for (int dw = 0; dw < 3; ++dw)
#pragma unroll 1
        for (int dx = 0; dx < 3; ++dx) {
            const float* xp = &xl[(dw * 3 + dx) * 676];
#pragma unroll
            for (int dy = 0; dy < 3; ++dy)
#pragma unroll
                for (int dz = 0; dz < 3; ++dz) {
                    float xv = xp[(yy + dy) * 26 + (zz + dz)];
                    const int t = ((dw * 3 + dx) * 3 + dy) * 3 + dz;
                    const float* wt0 = &Wp1g[t << 4];
                    const float* wt1 = &Wp1g[1296 + (t << 4)];
#pragma unroll
                    for (int c = 0; c < 16; ++c) {
                        a0[c] = fmaf(xv, wt0[c], a0[c]);
                        a1[c] = fmaf(xv, wt1[c], a1[c]);
                    }
                }
        }
    const size_t rec = (size_t)((w * 24 + xx) * 26 + yy + 1) * 26 + zz + 1;
    uint32_t pk[8];
#pragma unroll
    for (int cp = 0; cp < 8; ++cp) {
        float a = fmaxf(a0[2 * cp]     + b1[2 * cp],     0.f);
        float b = fmaxf(a0[2 * cp + 1] + b1[2 * cp + 1], 0.f);
        pk[cp] = f2bf(a) | (f2bf(b) << 16);
    }
    uint32_t* dst0 = y1p0 + rec * 8;
    *(uint4*)dst0       = make_uint4(pk[0], pk[1], pk[2], pk[3]);
    *(uint4*)(dst0 + 4) = make_uint4(pk[4], pk[5], pk[6], pk[7]);
#pragma unroll
    for (int cp = 0; cp < 8; ++cp) {
        float a = fmaxf(a1[2 * cp]     + b1[2 * cp],     0.f);
        float b = fmaxf(a1[2 * cp + 1] + b1[2 * cp + 1], 0.f);
        pk[cp] = f2bf(a) | (f2bf(b) << 16);
    }
    uint32_t* dst1 = y1p0 + (Y1P_PER_BR / 4) + rec * 8;
    *(uint4*)dst1       = make_uint4(pk[0], pk[1], pk[2], pk[3]);
    *(uint4*)(dst1 + 4) = make_uint4(pk[4], pk[5], pk[6], pk[7]);
}

// ---------------- conv2 v6: 32x32 z-shift MFMA on r11's engine -------------
// grid NB*3456; block 256 = 4 waves; wave owns 24 anchors (M padded to 32).
// A slab: [2 par][10 yl][13 zq] cells 48B (32B data) = 12480 B, dbuf.
#define RING_A 12480

__global__ __launch_bounds__(256) void conv2_mfma6(
    const char* __restrict__ bufbase, const char* __restrict__ Wp2T,
    const float* __restrict__ b2) {
    __shared__ char lds[2 * RING_A];
    const int tid = threadIdx.x, lane = tid & 63, wid = tid >> 6;
    const int bid = blockIdx.x, cpx = gridDim.x >> 3;
    const int wg = (bid & 7) * cpx + (bid >> 3);        // bijective (grid%8==0)
    const int n = wg / 3456, rr = wg - n * 3456;
    const int br = rr / 1728, b = rr - br * 1728;
    const char* y1p = bufbase + (size_t)n * PER_N + (size_t)br * Y1P_PER_BR;
    const char* Bb = Wp2T + (size_t)br * 110592 + lane * 16;
    ushort* y2b = (ushort*)(bufbase + (size_t)n * PER_N + Y2P_IN) + br * 16;
    const int w = b / 72, r0 = b % 72, xx = r0 / 3, y0 = (r0 % 3) * 8;

    const int row = lane & 31, khalf = lane >> 5;
    const int p_raw = wid * 24 + row;                   // anchor in y-group
    const int p = (p_raw < 96) ? p_raw : 95;            // clamp junk rows
    const int y_r = p / 12, zer = (p - y_r * 12) * 2;
    int aoff[12];
#pragma unroll
    for (int a = 0; a < 12; ++a) {
        int dy = a >> 2, dzA = a & 3;
        int zp = zer + dzA, par = zp & 1, zq = zp >> 1;
        aoff[a] = par * 6240 + ((y_r + dy) * 13 + zq) * 48 + khalf * 16;
    }
    // hoisted staging offsets (phase-invariant): parity-split slab, 780 slots
    int srelA[4], dstA[4]; bool actA[4];
#pragma unroll
    for (int it = 0; it < 4; ++it) {
        int g = tid + it * 256;
        actA[it] = g < 780;
        int cell = g / 3, part = g - cell * 3;
        int par_ = cell / 130, rem = cell - par_ * 130;
        int yl = rem / 13, zq = rem - yl * 13;
        int zp = zq * 2 + par_;
        srelA[it] = (yl * 26 + zp) * 32 + (part & 1) * 16;
        dstA[it] = ((tid & ~63) + it * 256) * 16;
    }

    f32x16 acc;
#pragma unroll
    for (int r = 0; r < 16; ++r) acc[r] = 0.f;

#define STAGEA(ph_, rb_) do {                                                       \
    int dw_ = (ph_) / 3, dx_ = (ph_) % 3;                                           \
    int wc_ = min(max(w + dw_ - 1, 0), 23), xc_ = min(max(xx + dx_ - 1, 0), 23);    \
    const char* inpl_ = y1p + (size_t)((wc_ * 24 + xc_) * 676 + y0 * 26) * 32;      \
    _Pragma("unroll")                                                               \
    for (int it_ = 0; it_ < 4; ++it_) {                                             \
        if (actA[it_])                                                              \
            __builtin_amdgcn_global_load_lds(                                       \
                (const __attribute__((address_space(1))) void*)(inpl_ + srelA[it_]),\
                (__attribute__((address_space(3))) void*)(lds + (rb_) + dstA[it_]), \
                16, 0, 0);                                                          \
    }                                                                               \
} while (0)

    STAGEA(0, 0);
    int ring = 0;
#pragma unroll 1
    for (int ph = 0; ph < 9; ++ph) {
        __syncthreads();                                 // slab[ring] ready
        if (ph < 8) STAGEA(ph + 1, ring ^ RING_A);
        // B fragments for this phase: JIT from L1-hot table
        const char* bp = Bb + ph * 12288;
        i32x4 bf[12];
#pragma unroll
        for (int a = 0; a < 12; ++a)
            bf[a] = *(const i32x4*)(bp + a * 1024);
        const int dw = ph / 3, dx = ph % 3;
        const bool valid = ((unsigned)(w + dw - 1) < 24u) && ((unsigned)(xx + dx - 1) < 24u);
        if (valid) {
#pragma unroll
            for (int a = 0; a < 12; ++a) {
                i32x4 avr = *(const i32x4*)(lds + ring + aoff[a]);
                acc = __builtin_amdgcn_mfma_f32_32x32x16_bf16(
                    __builtin_bit_cast(bf16x8, avr),
                    __builtin_bit_cast(bf16x8, bf[a]), acc, 0, 0, 0);
            }
        }
        ring ^= RING_A;
    }
#undef STAGEA

    // epilogue: D col=(co,s); Drow=(r&3)+8*(r>>2)+4*khalf; anchor=wid*24+Drow
    const int co = lane & 15, s = (lane >> 4) & 1;
    const float bb = b2[co];
    const int plane676 = (w * 24 + xx) * 676;
#pragma unroll
    for (int r = 0; r < 16; ++r) {
        int Drow = (r & 3) + 8 * (r >> 2) + 4 * khalf;
        if (Drow < 24) {
            int anc = wid * 24 + Drow;
            int yo = anc / 12, ze = (anc - yo * 12) * 2;
            float v = fmaxf(acc[r] + bb, 0.f);
            y2b[(size_t)(plane676 + (y0 + yo + 1) * 26 + (ze + s + 1)) * 32 + co] =
                (ushort)f2bf(v);
        }
    }
}

// ---------------- conv3: MFMA, branches in N cols 0/1; B from global regs --
#define RING3   20800

__global__ __launch_bounds__(256) void conv3_mfma(
    const char* __restrict__ bufbase, const char* __restrict__ Wp3c,
    const float* __restrict__ b3, float* __restrict__ out_c) {
    __shared__ char lds[2 * RING3];
    const int tid = threadIdx.x, lane = tid & 63, wid = tid >> 6;
    const int bid = blockIdx.x, cpx = gridDim.x >> 3;
    const int wg = (bid & 7) * cpx + (bid >> 3);        // bijective (grid%8==0)
    const int n = wg / 1728, r0a = wg - n * 1728;
    const char* y2p = bufbase + (size_t)n * PER_N + Y2P_IN;
    float* outn = out_c + (size_t)n * S4;
    const int w = r0a / 72, r0 = r0a % 72, xx = r0 / 3, y0 = (r0 % 3) * 8;

    const int col = lane & 15, g16 = (lane >> 4) & 3;
    const int pyA = (lane >> 3) & 1, pzA = lane & 7;
    int a3[9];
#pragma unroll
    for (int t = 0; t < 9; ++t) {
        int dy = t / 3, dz = t % 3;
        a3[t] = ((2 * wid + pyA + dy) * 26 + (pzA + dz)) * 80 + g16 * 16;
    }
    const bool bact = (col == 0 && g16 < 2) || (col == 1 && g16 >= 2);
    const int colsel = (col < 2) ? col : 0;
    const char* W3g = Wp3c + colsel * 2592 + (g16 & 1) * 16;
    const int bmask = bact ? -1 : 0;

    // hoisted staging offsets (phase-invariant)
    int srel3[6], dst3[6]; bool act3[6];
#pragma unroll
    for (int it = 0; it < 6; ++it) {
        int g = tid + it * 256;
        int c_ = g / 5, p_ = g - c_ * 5;
        act3[it] = (g < 1300) && (p_ < 4);
        srel3[it] = c_ * 64 + p_ * 16;
        dst3[it] = ((tid & ~63) + it * 256) * 16;
    }

    f32x4 acc[3];
#pragma unroll
    for (int m = 0; m < 3; ++m) acc[m] = f32x4{0.f, 0.f, 0.f, 0.f};

#define STAGE3(ph_, rb_) do {                                                       \
    int dw_ = (ph_) / 3, dx_ = (ph_) % 3;                                           \
    int wc_ = min(max(w + dw_ - 1, 0), 23), xc_ = min(max(xx + dx_ - 1, 0), 23);    \
    const char* slab_ = y2p + (size_t)((wc_ * 24 + xc_) * 676 + y0 * 26) * 64;      \
    _Pragma("unroll")                                                               \
    for (int it_ = 0; it_ < 6; ++it_) {                                             \
        if (act3[it_])                                                              \
            __builtin_amdgcn_global_load_lds(                                       \
                (const __attribute__((address_space(1))) void*)(slab_ + srel3[it_]),\
                (__attribute__((address_space(3))) void*)(lds + (rb_) + dst3[it_]), \
                16, 0, 0);                                                          \
    }                                                                               \
} while (0)

    STAGE3(0, 0);
    int ring = 0;
#pragma unroll 1
    for (int ph = 0; ph < 9; ++ph) {
        __syncthreads();
        if (ph < 8) STAGE3(ph + 1, ring ^ RING3);
        // B taps for this phase: JIT from L1-hot 5KB table
        i32x4 b9[9];
#pragma unroll
        for (int tl = 0; tl < 9; ++tl)
            b9[tl] = *(const i32x4*)(W3g + (ph * 9 + tl) * 32);
        int dw = ph / 3, dx = ph % 3;
        bool valid = ((unsigned)(w + dw - 1) < 24u) && ((unsigned)(xx + dx - 1) < 24u);
        if (valid) {
#pragma unroll
            for (int tl = 0; tl < 9; ++tl) {
                i32x4 bm;
                bm[0] = b9[tl][0] & bmask; bm[1] = b9[tl][1] & bmask;
                bm[2] = b9[tl][2] & bmask; bm[3] = b9[tl][3] & bmask;
#pragma unroll
                for (int m = 0; m < 3; ++m) {
                    i32x4 avr = *(const i32x4*)(lds + ring + a3[tl] + m * 640);
                    acc[m] = __builtin_amdgcn_mfma_f32_16x16x32_bf16(
                        __builtin_bit_cast(bf16x8, avr),
                        __builtin_bit_cast(bf16x8, bm), acc[m], 0, 0, 0);
                }
            }
        }
        ring ^= RING3;
    }
#undef STAGE3

    const float bv = b3[0];
    const int py = (lane >> 5) & 1, c4 = ((lane >> 4) & 1) * 4;
    const int yo = y0 + 2 * wid + py;
    float* obase = outn + ((size_t)(w * 24 + xx) * 24 + yo) * 24;
#pragma unroll
    for (int m = 0; m < 3; ++m) {
        float o[4];
#pragma unroll
        for (int r = 0; r < 4; ++r) {
            float mine = acc[m][r];
            float oth = __shfl_xor(mine, 1);
            o[r] = fmaxf(mine + bv, 0.f) + fmaxf(oth + bv, 0.f);
        }
        if (col == 0)
            *(float4*)(obase + m * 8 + c4) = make_float4(o[0], o[1], o[2], o[3]);
    }
}

extern "C" void kernel_launch(void* const* d_in, const int* in_sizes, int n_in,
                              void* d_out, int out_size, void* d_ws, size_t ws_size,
                              hipStream_t stream) {
    const float* x  = (const float*)d_in[0];
    const float* w1 = (const float*)d_in[1];
    const float* b1 = (const float*)d_in[2];
    const float* w2 = (const float*)d_in[3];
    const float* b2 = (const float*)d_in[4];
    const float* w3 = (const float*)d_in[5];
    const float* b3 = (const float*)d_in[6];
    float* out = (float*)d_out;
    char* ws = (char*)d_ws;
    if (ws_size < WS_NEED) return;

    float*  Wp1  = (float*)(ws + WP1_OFF);
    ushort* Wp3c = (ushort*)(ws + WP3C_OFF);
    ushort* Wp2T = (ushort*)(ws + WP2T_OFF);
    char* bufbase = ws + BUF_OFF;

    // ws-adaptive batch width (deterministic: depends only on ws_size)
    int NB = (int)((ws_size - BUF_OFF) / PER_N);
    if (NB > 8) NB = 8;
    if (NB < 1) return;
    const int nchunks = (8 + NB - 1) / NB;
    const int base = 8 / nchunks, rem = 8 % nchunks;

    prep_weights<<<444, 256, 0, stream>>>(w1, w2, w3, Wp1, Wp3c, Wp2T);
    halo_zero<<<NB * 576, 256, 0, stream>>>(bufbase);

    int c = 0;
    for (int k = 0; k < nchunks; ++k) {
        const int nb = base + (k < rem ? 1 : 0);
        conv1_plane2<<<nb * 576, 576, 0, stream>>>(
            x + (size_t)c * S4, Wp1, b1, bufbase);
        conv2_mfma6<<<nb * 3456, 256, 0, stream>>>(
            bufbase, (const char*)Wp2T, b2);
        conv3_mfma<<<nb * 1728, 256, 0, stream>>>(
            bufbase, (const char*)Wp3c, b3, out + (size_t)c * S4);
        c += nb;
    }
}

// Round 13
// 842.751 us; speedup vs baseline: 1.1584x; 1.1584x over previous
//
#include <hip/hip_runtime.h>
#include <hip/hip_bf16.h>
#include <stdint.h>

// ---------------------------------------------------------------------------
// out = net(x) + P(net(P(x))), P = swap (W,X)<->(Y,Z).  Equivariance:
// P(net(P(x);W)) = net(x; P_w(W)) -> one network, 2 weight branches.
//
// Round 13: merge proven-best kernels.  conv2 = r11 (48us/n; r12's 32x32
// variant hit its failure criterion -> reverted), with lane-constant asel
// hoisted.  conv3 = r12's JIT-B version (proven).  conv1/prep/halo/schedule
// = r11.
// ---------------------------------------------------------------------------

#define S   24
#define S2  576
#define S3  13824
#define S4  331776

typedef __attribute__((ext_vector_type(8)))  short bf16x8;
typedef __attribute__((ext_vector_type(4)))  float f32x4;
typedef __attribute__((ext_vector_type(4)))  int   i32x4;

__device__ __forceinline__ uint32_t f2bf(float f) {            // RNE f32->bf16
    uint32_t u = __float_as_uint(f);
    return (u + 0x7FFFu + ((u >> 16) & 1u)) >> 16;
}
__device__ __forceinline__ int permtap(int t) {                // (kw,kx,ky,kz)->(ky,kz,kw,kx)
    int kw = t / 27, kx = (t / 9) % 3, ky = (t / 3) % 3, kz = t % 3;
    return ky * 27 + kz * 9 + kw * 3 + kx;
}

// ---------------- workspace map (bytes) ----------------
#define WP1_OFF    0
#define WP3C_OFF   10368
#define WP2F_OFF   20736
#define BUF_OFF    131072
#define Y1P_PER_BR 12460032ull
#define Y2P_IN     24920064ull
#define PER_N      49840128ull
#define WS_NEED    (BUF_OFF + PER_N)

// ---------------- prep: pack weights (parallel) ----------------
__global__ void prep_weights(const float* __restrict__ w1, const float* __restrict__ w2,
                             const float* __restrict__ w3,
                             float* __restrict__ Wp1, ushort* __restrict__ Wp3c,
                             ushort* __restrict__ Wp2f) {
    const int bid = blockIdx.x, tid = threadIdx.x;
    if (bid < 180) {                                // 46080 Wp2f bf16 elements
        int i = bid * 256 + tid;
        int j = i & 7, l = (i >> 3) & 63, idx = i >> 9;
        int s = idx % 5, ph = (idx / 5) % 9, br = idx / 45;
        int tapl = 2 * s + (l >> 5);
        int co = l & 15, ci = ((l >> 4) & 1) * 8 + j;
        ushort v = 0;
        if (tapl < 9) {
            int dw = ph / 3, dx = ph % 3, dy = tapl / 3, dz = tapl % 3;
            int t = dw * 27 + dx * 9 + dy * 3 + dz;
            int ts = br ? permtap(t) : t;
            v = (ushort)f2bf(w2[(co * 16 + ci) * 81 + ts]);
        }
        Wp2f[i] = v;
    } else {
        int i = (bid - 180) * 256 + tid;
        if (i < 2592) {
            int ci = i & 15, t = (i >> 4) % 81, br = i / 1296;
            int ts = br ? permtap(t) : t;
            Wp1[i]  = w1[ci * 81 + ts];
            Wp3c[i] = (ushort)f2bf(w3[ci * 81 + ts]);
        }
    }
}

// ---------------- halo zero: (y,z) borders of y1p (2br) + y2p per buffer ---
__global__ __launch_bounds__(256) void halo_zero(char* __restrict__ bufbase) {
    const int tid = threadIdx.x;
    const int pb = blockIdx.x % 576, nb = blockIdx.x / 576;
    char* buf = bufbase + (size_t)nb * PER_N;
    for (int i = tid; i < 800; i += 256) {
        int cell, part, sect;
        if (i < 400) { sect = i / 200; cell = (i % 200) >> 1; part = i & 1; }
        else         { sect = 2;       cell = (i - 400) >> 2; part = i & 3; }
        int cy, cz;
        if (cell < 26)      { cy = 0;  cz = cell; }
        else if (cell < 52) { cy = 25; cz = cell - 26; }
        else if (cell < 76) { cy = cell - 51; cz = 0; }
        else                { cy = cell - 75; cz = 25; }
        size_t rec = (size_t)pb * 676 + cy * 26 + cz;
        char* dst;
        if (sect < 2) dst = buf + (size_t)sect * Y1P_PER_BR + rec * 32 + part * 16;
        else          dst = buf + Y2P_IN + rec * 64 + part * 16;
        *(uint4*)dst = make_uint4(0u, 0u, 0u, 0u);
    }
}

// ---------------- conv1: x (1ch f32) -> y1p (16ch bf16, padded), BOTH br ----
__global__ __launch_bounds__(576) void conv1_plane2(
    const float* __restrict__ x_c, const float* __restrict__ Wp1g,
    const float* __restrict__ b1, char* __restrict__ bufbase) {
    __shared__ float xl[9 * 676];
    const int tid = threadIdx.x;
    const int nl = blockIdx.x / 576, pb = blockIdx.x % 576;
    const float* xn = x_c + (size_t)nl * S4;
    uint32_t* y1p0 = (uint32_t*)(bufbase + (size_t)nl * PER_N);
    const int w = pb / 24, xx = pb % 24;
    for (int g = tid; g < 6084; g += 576) {
        int wi = g / 2028, r1 = g - wi * 2028;
        int xi = r1 / 676, r2 = r1 - xi * 676;
        int yp = r2 / 26, zp = r2 - yp * 26;
        int ws_ = w + wi - 1, xs = xx + xi - 1, ys = yp - 1, zs = zp - 1;
        float v = 0.f;
        if ((unsigned)ws_ < 24u && (unsigned)xs < 24u && (unsigned)ys < 24u && (unsigned)zs < 24u)
            v = xn[((ws_ * 24 + xs) * 24 + ys) * 24 + zs];
        xl[g] = v;
    }
    __syncthreads();
    const int yy = tid / 24, zz = tid - (tid / 24) * 24;
    float a0[16], a1[16];
#pragma unroll
    for (int c = 0; c < 16; ++c) { a0[c] = 0.f; a1[c] = 0.f; }
#pragma unroll 1
    for (int dw = 0; dw < 3; ++dw)
#pragma unroll 1
        for (int dx = 0; dx < 3; ++dx) {
            const float* xp = &xl[(dw * 3 + dx) * 676];
#pragma unroll
            for (int dy = 0; dy < 3; ++dy)
#pragma unroll
                for (int dz = 0; dz < 3; ++dz) {
                    float xv = xp[(yy + dy) * 26 + (zz + dz)];
                    const int t = ((dw * 3 + dx) * 3 + dy) * 3 + dz;
                    const float* wt0 = &Wp1g[t << 4];
                    const float* wt1 = &Wp1g[1296 + (t << 4)];
#pragma unroll
                    for (int c = 0; c < 16; ++c) {
                        a0[c] = fmaf(xv, wt0[c], a0[c]);
                        a1[c] = fmaf(xv, wt1[c], a1[c]);
                    }
                }
        }
    const size_t rec = (size_t)((w * 24 + xx) * 26 + yy + 1) * 26 + zz + 1;
    uint32_t pk[8];
#pragma unroll
    for (int cp = 0; cp < 8; ++cp) {
        float a = fmaxf(a0[2 * cp]     + b1[2 * cp],     0.f);
        float b = fmaxf(a0[2 * cp + 1] + b1[2 * cp + 1], 0.f);
        pk[cp] = f2bf(a) | (f2bf(b) << 16);
    }
    uint32_t* dst0 = y1p0 + rec * 8;
    *(uint4*)dst0       = make_uint4(pk[0], pk[1], pk[2], pk[3]);
    *(uint4*)(dst0 + 4) = make_uint4(pk[4], pk[5], pk[6], pk[7]);
#pragma unroll
    for (int cp = 0; cp < 8; ++cp) {
        float a = fmaxf(a1[2 * cp]     + b1[2 * cp],     0.f);
        float b = fmaxf(a1[2 * cp + 1] + b1[2 * cp + 1], 0.f);
        pk[cp] = f2bf(a) | (f2bf(b) << 16);
    }
    uint32_t* dst1 = y1p0 + (Y1P_PER_BR / 4) + rec * 8;
    *(uint4*)dst1       = make_uint4(pk[0], pk[1], pk[2], pk[3]);
    *(uint4*)(dst1 + 4) = make_uint4(pk[4], pk[5], pk[6], pk[7]);
}

// ---------------- conv2: r11 proven (B->regs, hoisted staging + asel) ------
// grid NB*3456; block 256 = 4 waves; LDS ring 2 x 12480 (A only).
#define RING_A 12480

__global__ __launch_bounds__(256) void conv2_mfma(
    const char* __restrict__ bufbase, const char* __restrict__ Wp2f0,
    const float* __restrict__ b2) {
    __shared__ char lds[2 * RING_A];
    const int tid = threadIdx.x, lane = tid & 63, wid = tid >> 6;
    const int bid = blockIdx.x, cpx = gridDim.x >> 3;
    const int wg = (bid & 7) * cpx + (bid >> 3);        // bijective (grid%8==0)
    const int n = wg / 3456, rr = wg - n * 3456;
    const int br = rr / 1728, b = rr - br * 1728;
    const char* y1p = bufbase + (size_t)n * PER_N + (size_t)br * Y1P_PER_BR;
    const char* Bb = Wp2f0 + br * 46080 + lane * 16;
    ushort* y2b = (ushort*)(bufbase + (size_t)n * PER_N + Y2P_IN) + br * 16;
    const int w = b / 72, r0 = b % 72, xx = r0 / 3, y0 = (r0 % 3) * 8;

    const int h = (lane >> 4) & 1;
    const bool th = lane >= 32;
    const int pyA = (lane >> 3) & 1, pzA = lane & 7;
    int aw[5];                                          // lane-constant A offsets
#pragma unroll
    for (int s = 0; s < 5; ++s) {
        int tA = th ? ((2 * s + 1 < 9) ? 2 * s + 1 : 8) : 2 * s;
        int dy = tA / 3, dz = tA % 3;
        aw[s] = ((2 * wid + pyA + dy) * 26 + (pzA + dz)) * 48 + h * 16;
    }
    // hoisted staging offsets (phase-invariant)
    int srelA[4], dstA[4]; bool actA[4];
#pragma unroll
    for (int it = 0; it < 4; ++it) {
        int g = tid + it * 256;
        actA[it] = g < 780;
        int row = g / 3, part = g - row * 3;
        srelA[it] = row * 32 + (part & 1) * 16;
        dstA[it] = ((tid & ~63) + it * 256) * 16;
    }

    f32x4 acc[3];
#pragma unroll
    for (int m = 0; m < 3; ++m) acc[m] = f32x4{0.f, 0.f, 0.f, 0.f};

#define STAGEA(ph_, rb_) do {                                                       \
    int dw_ = (ph_) / 3, dx_ = (ph_) % 3;                                           \
    int wc_ = min(max(w + dw_ - 1, 0), 23), xc_ = min(max(xx + dx_ - 1, 0), 23);    \
    const char* inpl_ = y1p + (size_t)((wc_ * 24 + xc_) * 676 + y0 * 26) * 32;      \
    _Pragma("unroll")                                                               \
    for (int it_ = 0; it_ < 4; ++it_) {                                             \
        if (actA[it_])                                                              \
            __builtin_amdgcn_global_load_lds(                                       \
                (const __attribute__((address_space(1))) void*)(inpl_ + srelA[it_]),\
                (__attribute__((address_space(3))) void*)(lds + (rb_) + dstA[it_]), \
                16, 0, 0);                                                          \
    }                                                                               \
} while (0)

    i32x4 bcur[5], bnxt[5];
#pragma unroll
    for (int s = 0; s < 5; ++s) bcur[s] = *(const i32x4*)(Bb + s * 1024);
    STAGEA(0, 0);

    int ring = 0;
#pragma unroll 1
    for (int ph = 0; ph < 9; ++ph) {
        __syncthreads();                                 // slab[ring] ready
        if (ph < 8) {
            STAGEA(ph + 1, ring ^ RING_A);
            const char* bp = Bb + (ph + 1) * 5120;
#pragma unroll
            for (int s = 0; s < 5; ++s) bnxt[s] = *(const i32x4*)(bp + s * 1024);
        }
        const int dw = ph / 3, dx = ph % 3;
        const bool valid = ((unsigned)(w + dw - 1) < 24u) && ((unsigned)(xx + dx - 1) < 24u);
        if (valid) {
#pragma unroll
            for (int s = 0; s < 5; ++s) {
                const char* ap = lds + ring + aw[s];
#pragma unroll
                for (int m = 0; m < 3; ++m) {
                    i32x4 avr = *(const i32x4*)(ap + m * 384);
                    acc[m] = __builtin_amdgcn_mfma_f32_16x16x32_bf16(
                        __builtin_bit_cast(bf16x8, avr),
                        __builtin_bit_cast(bf16x8, bcur[s]), acc[m], 0, 0, 0);
                }
            }
        }
        ring ^= RING_A;
#pragma unroll
        for (int s = 0; s < 5; ++s) bcur[s] = bnxt[s];
    }
#undef STAGEA

    // epilogue into padded y2p: record = plane*676 + (y+1)*26 + 1 + z
    const int co = lane & 15;
    const float bb = b2[co];
    const int py = (lane >> 5) & 1, c4 = ((lane >> 4) & 1) * 4;
    const size_t planeb = (size_t)(w * 24 + xx) * 676;
    const size_t rowb = planeb + (size_t)(y0 + 2 * wid + py + 1) * 26 + 1;
#pragma unroll
    for (int m = 0; m < 3; ++m)
#pragma unroll
        for (int r = 0; r < 4; ++r) {
            float v = fmaxf(acc[m][r] + bb, 0.f);
            y2b[(rowb + m * 8 + c4 + r) * 32 + co] = (ushort)f2bf(v);
        }
}

// ---------------- conv3: r12 proven (B taps JIT from global) ---------------
#define RING3   20800

__global__ __launch_bounds__(256) void conv3_mfma(
    const char* __restrict__ bufbase, const char* __restrict__ Wp3c,
    const float* __restrict__ b3, float* __restrict__ out_c) {
    __shared__ char lds[2 * RING3];
    const int tid = threadIdx.x, lane = tid & 63, wid = tid >> 6;
    const int bid = blockIdx.x, cpx = gridDim.x >> 3;
    const int wg = (bid & 7) * cpx + (bid >> 3);        // bijective (grid%8==0)
    const int n = wg / 1728, r0a = wg - n * 1728;
    const char* y2p = bufbase + (size_t)n * PER_N + Y2P_IN;
    float* outn = out_c + (size_t)n * S4;
    const int w = r0a / 72, r0 = r0a % 72, xx = r0 / 3, y0 = (r0 % 3) * 8;

    const int col = lane & 15, g16 = (lane >> 4) & 3;
    const int pyA = (lane >> 3) & 1, pzA = lane & 7;
    int a3[9];
#pragma unroll
    for (int t = 0; t < 9; ++t) {
        int dy = t / 3, dz = t % 3;
        a3[t] = ((2 * wid + pyA + dy) * 26 + (pzA + dz)) * 80 + g16 * 16;
    }
    const bool bact = (col == 0 && g16 < 2) || (col == 1 && g16 >= 2);
    const int colsel = (col < 2) ? col : 0;
    const char* W3g = Wp3c + colsel * 2592 + (g16 & 1) * 16;
    const int bmask = bact ? -1 : 0;

    // hoisted staging offsets (phase-invariant)
    int srel3[6], dst3[6]; bool act3[6];
#pragma unroll
    for (int it = 0; it < 6; ++it) {
        int g = tid + it * 256;
        int c_ = g / 5, p_ = g - c_ * 5;
        act3[it] = (g < 1300) && (p_ < 4);
        srel3[it] = c_ * 64 + p_ * 16;
        dst3[it] = ((tid & ~63) + it * 256) * 16;
    }

    f32x4 acc[3];
#pragma unroll
    for (int m = 0; m < 3; ++m) acc[m] = f32x4{0.f, 0.f, 0.f, 0.f};

#define STAGE3(ph_, rb_) do {                                                       \
    int dw_ = (ph_) / 3, dx_ = (ph_) % 3;                                           \
    int wc_ = min(max(w + dw_ - 1, 0), 23), xc_ = min(max(xx + dx_ - 1, 0), 23);    \
    const char* slab_ = y2p + (size_t)((wc_ * 24 + xc_) * 676 + y0 * 26) * 64;      \
    _Pragma("unroll")                                                               \
    for (int it_ = 0; it_ < 6; ++it_) {                                             \
        if (act3[it_])                                                              \
            __builtin_amdgcn_global_load_lds(                                       \
                (const __attribute__((address_space(1))) void*)(slab_ + srel3[it_]),\
                (__attribute__((address_space(3))) void*)(lds + (rb_) + dst3[it_]), \
                16, 0, 0);                                                          \
    }                                                                               \
} while (0)

    STAGE3(0, 0);
    int ring = 0;
#pragma unroll 1
    for (int ph = 0; ph < 9; ++ph) {
        __syncthreads();
        if (ph < 8) STAGE3(ph + 1, ring ^ RING3);
        // B taps for this phase: JIT from L1-hot 5KB table
        i32x4 b9[9];
#pragma unroll
        for (int tl = 0; tl < 9; ++tl)
            b9[tl] = *(const i32x4*)(W3g + (ph * 9 + tl) * 32);
        int dw = ph / 3, dx = ph % 3;
        bool valid = ((unsigned)(w + dw - 1) < 24u) && ((unsigned)(xx + dx - 1) < 24u);
        if (valid) {
#pragma unroll
            for (int tl = 0; tl < 9; ++tl) {
                i32x4 bm;
                bm[0] = b9[tl][0] & bmask; bm[1] = b9[tl][1] & bmask;
                bm[2] = b9[tl][2] & bmask; bm[3] = b9[tl][3] & bmask;
#pragma unroll
                for (int m = 0; m < 3; ++m) {
                    i32x4 avr = *(const i32x4*)(lds + ring + a3[tl] + m * 640);
                    acc[m] = __builtin_amdgcn_mfma_f32_16x16x32_bf16(
                        __builtin_bit_cast(bf16x8, avr),
                        __builtin_bit_cast(bf16x8, bm), acc[m], 0, 0, 0);
                }
            }
        }
        ring ^= RING3;
    }
#undef STAGE3

    const float bv = b3[0];
    const int py = (lane >> 5) & 1, c4 = ((lane >> 4) & 1) * 4;
    const int yo = y0 + 2 * wid + py;
    float* obase = outn + ((size_t)(w * 24 + xx) * 24 + yo) * 24;
#pragma unroll
    for (int m = 0; m < 3; ++m) {
        float o[4];
#pragma unroll
        for (int r = 0; r < 4; ++r) {
            float mine = acc[m][r];
            float oth = __shfl_xor(mine, 1);
            o[r] = fmaxf(mine + bv, 0.f) + fmaxf(oth + bv, 0.f);
        }
        if (col == 0)
            *(float4*)(obase + m * 8 + c4) = make_float4(o[0], o[1], o[2], o[3]);
    }
}

extern "C" void kernel_launch(void* const* d_in, const int* in_sizes, int n_in,
                              void* d_out, int out_size, void* d_ws, size_t ws_size,
                              hipStream_t stream) {
    const float* x  = (const float*)d_in[0];
    const float* w1 = (const float*)d_in[1];
    const float* b1 = (const float*)d_in[2];
    const float* w2 = (const float*)d_in[3];
    const float* b2 = (const float*)d_in[4];
    const float* w3 = (const float*)d_in[5];
    const float* b3 = (const float*)d_in[6];
    float* out = (float*)d_out;
    char* ws = (char*)d_ws;
    if (ws_size < WS_NEED) return;

    float*  Wp1  = (float*)(ws + WP1_OFF);
    ushort* Wp3c = (ushort*)(ws + WP3C_OFF);
    ushort* Wp2f = (ushort*)(ws + WP2F_OFF);
    char* bufbase = ws + BUF_OFF;

    // ws-adaptive batch width (deterministic: depends only on ws_size)
    int NB = (int)((ws_size - BUF_OFF) / PER_N);
    if (NB > 8) NB = 8;
    if (NB < 1) return;
    const int nchunks = (8 + NB - 1) / NB;
    const int base = 8 / nchunks, rem = 8 % nchunks;

    prep_weights<<<191, 256, 0, stream>>>(w1, w2, w3, Wp1, Wp3c, Wp2f);
    halo_zero<<<NB * 576, 256, 0, stream>>>(bufbase);

    int c = 0;
    for (int k = 0; k < nchunks; ++k) {
        const int nb = base + (k < rem ? 1 : 0);
        conv1_plane2<<<nb * 576, 576, 0, stream>>>(
            x + (size_t)c * S4, Wp1, b1, bufbase);
        conv2_mfma<<<nb * 3456, 256, 0, stream>>>(
            bufbase, (const char*)Wp2f, b2);
        conv3_mfma<<<nb * 1728, 256, 0, stream>>>(
            bufbase, (const char*)Wp3c, b3, out + (size_t)c * S4);
        c += nb;
    }
}

// Round 14
// 834.499 us; speedup vs baseline: 1.1699x; 1.0099x over previous
//
#include <hip/hip_runtime.h>
#include <hip/hip_bf16.h>
#include <stdint.h>

// ---------------------------------------------------------------------------
// out = net(x) + P(net(P(x))), P = swap (W,X)<->(Y,Z).  Equivariance:
// P(net(P(x);W)) = net(x; P_w(W)) -> one network, 2 weight branches.
//
// Round 14: r13 with the conv2/conv3 phase loops FULLY UNROLLED (9 iters,
// compile-time ring select).  Kills the per-phase bcur=bnxt register
// rotation (20 v_mov/phase/thread -> SSA renames) and lets the compiler
// hoist B prefetches into MFMA shadows.  No other changes.
// ---------------------------------------------------------------------------

#define S   24
#define S2  576
#define S3  13824
#define S4  331776

typedef __attribute__((ext_vector_type(8)))  short bf16x8;
typedef __attribute__((ext_vector_type(4)))  float f32x4;
typedef __attribute__((ext_vector_type(4)))  int   i32x4;

__device__ __forceinline__ uint32_t f2bf(float f) {            // RNE f32->bf16
    uint32_t u = __float_as_uint(f);
    return (u + 0x7FFFu + ((u >> 16) & 1u)) >> 16;
}
__device__ __forceinline__ int permtap(int t) {                // (kw,kx,ky,kz)->(ky,kz,kw,kx)
    int kw = t / 27, kx = (t / 9) % 3, ky = (t / 3) % 3, kz = t % 3;
    return ky * 27 + kz * 9 + kw * 3 + kx;
}

// ---------------- workspace map (bytes) ----------------
#define WP1_OFF    0
#define WP3C_OFF   10368
#define WP2F_OFF   20736
#define BUF_OFF    131072
#define Y1P_PER_BR 12460032ull
#define Y2P_IN     24920064ull
#define PER_N      49840128ull
#define WS_NEED    (BUF_OFF + PER_N)

// ---------------- prep: pack weights (parallel) ----------------
__global__ void prep_weights(const float* __restrict__ w1, const float* __restrict__ w2,
                             const float* __restrict__ w3,
                             float* __restrict__ Wp1, ushort* __restrict__ Wp3c,
                             ushort* __restrict__ Wp2f) {
    const int bid = blockIdx.x, tid = threadIdx.x;
    if (bid < 180) {                                // 46080 Wp2f bf16 elements
        int i = bid * 256 + tid;
        int j = i & 7, l = (i >> 3) & 63, idx = i >> 9;
        int s = idx % 5, ph = (idx / 5) % 9, br = idx / 45;
        int tapl = 2 * s + (l >> 5);
        int co = l & 15, ci = ((l >> 4) & 1) * 8 + j;
        ushort v = 0;
        if (tapl < 9) {
            int dw = ph / 3, dx = ph % 3, dy = tapl / 3, dz = tapl % 3;
            int t = dw * 27 + dx * 9 + dy * 3 + dz;
            int ts = br ? permtap(t) : t;
            v = (ushort)f2bf(w2[(co * 16 + ci) * 81 + ts]);
        }
        Wp2f[i] = v;
    } else {
        int i = (bid - 180) * 256 + tid;
        if (i < 2592) {
            int ci = i & 15, t = (i >> 4) % 81, br = i / 1296;
            int ts = br ? permtap(t) : t;
            Wp1[i]  = w1[ci * 81 + ts];
            Wp3c[i] = (ushort)f2bf(w3[ci * 81 + ts]);
        }
    }
}

// ---------------- halo zero: (y,z) borders of y1p (2br) + y2p per buffer ---
__global__ __launch_bounds__(256) void halo_zero(char* __restrict__ bufbase) {
    const int tid = threadIdx.x;
    const int pb = blockIdx.x % 576, nb = blockIdx.x / 576;
    char* buf = bufbase + (size_t)nb * PER_N;
    for (int i = tid; i < 800; i += 256) {
        int cell, part, sect;
        if (i < 400) { sect = i / 200; cell = (i % 200) >> 1; part = i & 1; }
        else         { sect = 2;       cell = (i - 400) >> 2; part = i & 3; }
        int cy, cz;
        if (cell < 26)      { cy = 0;  cz = cell; }
        else if (cell < 52) { cy = 25; cz = cell - 26; }
        else if (cell < 76) { cy = cell - 51; cz = 0; }
        else                { cy = cell - 75; cz = 25; }
        size_t rec = (size_t)pb * 676 + cy * 26 + cz;
        char* dst;
        if (sect < 2) dst = buf + (size_t)sect * Y1P_PER_BR + rec * 32 + part * 16;
        else          dst = buf + Y2P_IN + rec * 64 + part * 16;
        *(uint4*)dst = make_uint4(0u, 0u, 0u, 0u);
    }
}

// ---------------- conv1: x (1ch f32) -> y1p (16ch bf16, padded), BOTH br ----
__global__ __launch_bounds__(576) void conv1_plane2(
    const float* __restrict__ x_c, const float* __restrict__ Wp1g,
    const float* __restrict__ b1, char* __restrict__ bufbase) {
    __shared__ float xl[9 * 676];
    const int tid = threadIdx.x;
    const int nl = blockIdx.x / 576, pb = blockIdx.x % 576;
    const float* xn = x_c + (size_t)nl * S4;
    uint32_t* y1p0 = (uint32_t*)(bufbase + (size_t)nl * PER_N);
    const int w = pb / 24, xx = pb % 24;
    for (int g = tid; g < 6084; g += 576) {
        int wi = g / 2028, r1 = g - wi * 2028;
        int xi = r1 / 676, r2 = r1 - xi * 676;
        int yp = r2 / 26, zp = r2 - yp * 26;
        int ws_ = w + wi - 1, xs = xx + xi - 1, ys = yp - 1, zs = zp - 1;
        float v = 0.f;
        if ((unsigned)ws_ < 24u && (unsigned)xs < 24u && (unsigned)ys < 24u && (unsigned)zs < 24u)
            v = xn[((ws_ * 24 + xs) * 24 + ys) * 24 + zs];
        xl[g] = v;
    }
    __syncthreads();
    const int yy = tid / 24, zz = tid - (tid / 24) * 24;
    float a0[16], a1[16];
#pragma unroll
    for (int c = 0; c < 16; ++c) { a0[c] = 0.f; a1[c] = 0.f; }
#pragma unroll 1
    for (int dw = 0; dw < 3; ++dw)
#pragma unroll 1
        for (int dx = 0; dx < 3; ++dx) {
            const float* xp = &xl[(dw * 3 + dx) * 676];
#pragma unroll
            for (int dy = 0; dy < 3; ++dy)
#pragma unroll
                for (int dz = 0; dz < 3; ++dz) {
                    float xv = xp[(yy + dy) * 26 + (zz + dz)];
                    const int t = ((dw * 3 + dx) * 3 + dy) * 3 + dz;
                    const float* wt0 = &Wp1g[t << 4];
                    const float* wt1 = &Wp1g[1296 + (t << 4)];
#pragma unroll
                    for (int c = 0; c < 16; ++c) {
                        a0[c] = fmaf(xv, wt0[c], a0[c]);
                        a1[c] = fmaf(xv, wt1[c], a1[c]);
                    }
                }
        }
    const size_t rec = (size_t)((w * 24 + xx) * 26 + yy + 1) * 26 + zz + 1;
    uint32_t pk[8];
#pragma unroll
    for (int cp = 0; cp < 8; ++cp) {
        float a = fmaxf(a0[2 * cp]     + b1[2 * cp],     0.f);
        float b = fmaxf(a0[2 * cp + 1] + b1[2 * cp + 1], 0.f);
        pk[cp] = f2bf(a) | (f2bf(b) << 16);
    }
    uint32_t* dst0 = y1p0 + rec * 8;
    *(uint4*)dst0       = make_uint4(pk[0], pk[1], pk[2], pk[3]);
    *(uint4*)(dst0 + 4) = make_uint4(pk[4], pk[5], pk[6], pk[7]);
#pragma unroll
    for (int cp = 0; cp < 8; ++cp) {
        float a = fmaxf(a1[2 * cp]     + b1[2 * cp],     0.f);
        float b = fmaxf(a1[2 * cp + 1] + b1[2 * cp + 1], 0.f);
        pk[cp] = f2bf(a) | (f2bf(b) << 16);
    }
    uint32_t* dst1 = y1p0 + (Y1P_PER_BR / 4) + rec * 8;
    *(uint4*)dst1       = make_uint4(pk[0], pk[1], pk[2], pk[3]);
    *(uint4*)(dst1 + 4) = make_uint4(pk[4], pk[5], pk[6], pk[7]);
}

// ---------------- conv2: r11 proven skeleton, phase loop fully unrolled ----
// grid NB*3456; block 256 = 4 waves; LDS ring 2 x 12480 (A only).
#define RING_A 12480

__global__ __launch_bounds__(256) void conv2_mfma(
    const char* __restrict__ bufbase, const char* __restrict__ Wp2f0,
    const float* __restrict__ b2) {
    __shared__ char lds[2 * RING_A];
    const int tid = threadIdx.x, lane = tid & 63, wid = tid >> 6;
    const int bid = blockIdx.x, cpx = gridDim.x >> 3;
    const int wg = (bid & 7) * cpx + (bid >> 3);        // bijective (grid%8==0)
    const int n = wg / 3456, rr = wg - n * 3456;
    const int br = rr / 1728, b = rr - br * 1728;
    const char* y1p = bufbase + (size_t)n * PER_N + (size_t)br * Y1P_PER_BR;
    const char* Bb = Wp2f0 + br * 46080 + lane * 16;
    ushort* y2b = (ushort*)(bufbase + (size_t)n * PER_N + Y2P_IN) + br * 16;
    const int w = b / 72, r0 = b % 72, xx = r0 / 3, y0 = (r0 % 3) * 8;

    const int h = (lane >> 4) & 1;
    const bool th = lane >= 32;
    const int pyA = (lane >> 3) & 1, pzA = lane & 7;
    int aw[5];                                          // lane-constant A offsets
#pragma unroll
    for (int s = 0; s < 5; ++s) {
        int tA = th ? ((2 * s + 1 < 9) ? 2 * s + 1 : 8) : 2 * s;
        int dy = tA / 3, dz = tA % 3;
        aw[s] = ((2 * wid + pyA + dy) * 26 + (pzA + dz)) * 48 + h * 16;
    }
    // hoisted staging offsets (phase-invariant)
    int srelA[4], dstA[4]; bool actA[4];
#pragma unroll
    for (int it = 0; it < 4; ++it) {
        int g = tid + it * 256;
        actA[it] = g < 780;
        int row = g / 3, part = g - row * 3;
        srelA[it] = row * 32 + (part & 1) * 16;
        dstA[it] = ((tid & ~63) + it * 256) * 16;
    }

    f32x4 acc[3];
#pragma unroll
    for (int m = 0; m < 3; ++m) acc[m] = f32x4{0.f, 0.f, 0.f, 0.f};

#define STAGEA(ph_, rb_) do {                                                       \
    int dw_ = (ph_) / 3, dx_ = (ph_) % 3;                                           \
    int wc_ = min(max(w + dw_ - 1, 0), 23), xc_ = min(max(xx + dx_ - 1, 0), 23);    \
    const char* inpl_ = y1p + (size_t)((wc_ * 24 + xc_) * 676 + y0 * 26) * 32;      \
    _Pragma("unroll")                                                               \
    for (int it_ = 0; it_ < 4; ++it_) {                                             \
        if (actA[it_])                                                              \
            __builtin_amdgcn_global_load_lds(                                       \
                (const __attribute__((address_space(1))) void*)(inpl_ + srelA[it_]),\
                (__attribute__((address_space(3))) void*)(lds + (rb_) + dstA[it_]), \
                16, 0, 0);                                                          \
    }                                                                               \
} while (0)

    i32x4 bcur[5], bnxt[5];
#pragma unroll
    for (int s = 0; s < 5; ++s) bcur[s] = *(const i32x4*)(Bb + s * 1024);
    STAGEA(0, 0);

#pragma unroll
    for (int ph = 0; ph < 9; ++ph) {                    // FULL unroll: ring const
        const int ring = (ph & 1) * RING_A;
        __syncthreads();                                 // slab[ring] ready
        if (ph < 8) {
            STAGEA(ph + 1, ring ^ RING_A);
            const char* bp = Bb + (ph + 1) * 5120;
#pragma unroll
            for (int s = 0; s < 5; ++s) bnxt[s] = *(const i32x4*)(bp + s * 1024);
        }
        const int dw = ph / 3, dx = ph % 3;
        const bool valid = ((unsigned)(w + dw - 1) < 24u) && ((unsigned)(xx + dx - 1) < 24u);
        if (valid) {
#pragma unroll
            for (int s = 0; s < 5; ++s) {
                const char* ap = lds + ring + aw[s];
#pragma unroll
                for (int m = 0; m < 3; ++m) {
                    i32x4 avr = *(const i32x4*)(ap + m * 384);
                    acc[m] = __builtin_amdgcn_mfma_f32_16x16x32_bf16(
                        __builtin_bit_cast(bf16x8, avr),
                        __builtin_bit_cast(bf16x8, bcur[s]), acc[m], 0, 0, 0);
                }
            }
        }
#pragma unroll
        for (int s = 0; s < 5; ++s) bcur[s] = bnxt[s];   // SSA-renamed when unrolled
    }
#undef STAGEA

    // epilogue into padded y2p: record = plane*676 + (y+1)*26 + 1 + z
    const int co = lane & 15;
    const float bb = b2[co];
    const int py = (lane >> 5) & 1, c4 = ((lane >> 4) & 1) * 4;
    const size_t planeb = (size_t)(w * 24 + xx) * 676;
    const size_t rowb = planeb + (size_t)(y0 + 2 * wid + py + 1) * 26 + 1;
#pragma unroll
    for (int m = 0; m < 3; ++m)
#pragma unroll
        for (int r = 0; r < 4; ++r) {
            float v = fmaxf(acc[m][r] + bb, 0.f);
            y2b[(rowb + m * 8 + c4 + r) * 32 + co] = (ushort)f2bf(v);
        }
}

// ---------------- conv3: r12 proven (JIT B), phase loop fully unrolled -----
#define RING3   20800

__global__ __launch_bounds__(256) void conv3_mfma(
    const char* __restrict__ bufbase, const char* __restrict__ Wp3c,
    const float* __restrict__ b3, float* __restrict__ out_c) {
    __shared__ char lds[2 * RING3];
    const int tid = threadIdx.x, lane = tid & 63, wid = tid >> 6;
    const int bid = blockIdx.x, cpx = gridDim.x >> 3;
    const int wg = (bid & 7) * cpx + (bid >> 3);        // bijective (grid%8==0)
    const int n = wg / 1728, r0a = wg - n * 1728;
    const char* y2p = bufbase + (size_t)n * PER_N + Y2P_IN;
    float* outn = out_c + (size_t)n * S4;
    const int w = r0a / 72, r0 = r0a % 72, xx = r0 / 3, y0 = (r0 % 3) * 8;

    const int col = lane & 15, g16 = (lane >> 4) & 3;
    const int pyA = (lane >> 3) & 1, pzA = lane & 7;
    int a3[9];
#pragma unroll
    for (int t = 0; t < 9; ++t) {
        int dy = t / 3, dz = t % 3;
        a3[t] = ((2 * wid + pyA + dy) * 26 + (pzA + dz)) * 80 + g16 * 16;
    }
    const bool bact = (col == 0 && g16 < 2) || (col == 1 && g16 >= 2);
    const int colsel = (col < 2) ? col : 0;
    const char* W3g = Wp3c + colsel * 2592 + (g16 & 1) * 16;
    const int bmask = bact ? -1 : 0;

    // hoisted staging offsets (phase-invariant)
    int srel3[6], dst3[6]; bool act3[6];
#pragma unroll
    for (int it = 0; it < 6; ++it) {
        int g = tid + it * 256;
        int c_ = g / 5, p_ = g - c_ * 5;
        act3[it] = (g < 1300) && (p_ < 4);
        srel3[it] = c_ * 64 + p_ * 16;
        dst3[it] = ((tid & ~63) + it * 256) * 16;
    }

    f32x4 acc[3];
#pragma unroll
    for (int m = 0; m < 3; ++m) acc[m] = f32x4{0.f, 0.f, 0.f, 0.f};

#define STAGE3(ph_, rb_) do {                                                       \
    int dw_ = (ph_) / 3, dx_ = (ph_) % 3;                                           \
    int wc_ = min(max(w + dw_ - 1, 0), 23), xc_ = min(max(xx + dx_ - 1, 0), 23);    \
    const char* slab_ = y2p + (size_t)((wc_ * 24 + xc_) * 676 + y0 * 26) * 64;      \
    _Pragma("unroll")                                                               \
    for (int it_ = 0; it_ < 6; ++it_) {                                             \
        if (act3[it_])                                                              \
            __builtin_amdgcn_global_load_lds(                                       \
                (const __attribute__((address_space(1))) void*)(slab_ + srel3[it_]),\
                (__attribute__((address_space(3))) void*)(lds + (rb_) + dst3[it_]), \
                16, 0, 0);                                                          \
    }                                                                               \
} while (0)

    STAGE3(0, 0);
#pragma unroll
    for (int ph = 0; ph < 9; ++ph) {                    // FULL unroll: ring const
        const int ring = (ph & 1) * RING3;
        __syncthreads();
        if (ph < 8) STAGE3(ph + 1, ring ^ RING3);
        // B taps for this phase: JIT from L1-hot 5KB table
        i32x4 b9[9];
#pragma unroll
        for (int tl = 0; tl < 9; ++tl)
            b9[tl] = *(const i32x4*)(W3g + (ph * 9 + tl) * 32);
        const int dw = ph / 3, dx = ph % 3;
        const bool valid = ((unsigned)(w + dw - 1) < 24u) && ((unsigned)(xx + dx - 1) < 24u);
        if (valid) {
#pragma unroll
            for (int tl = 0; tl < 9; ++tl) {
                i32x4 bm;
                bm[0] = b9[tl][0] & bmask; bm[1] = b9[tl][1] & bmask;
                bm[2] = b9[tl][2] & bmask; bm[3] = b9[tl][3] & bmask;
#pragma unroll
                for (int m = 0; m < 3; ++m) {
                    i32x4 avr = *(const i32x4*)(lds + ring + a3[tl] + m * 640);
                    acc[m] = __builtin_amdgcn_mfma_f32_16x16x32_bf16(
                        __builtin_bit_cast(bf16x8, avr),
                        __builtin_bit_cast(bf16x8, bm), acc[m], 0, 0, 0);
                }
            }
        }
    }
#undef STAGE3

    const float bv = b3[0];
    const int py = (lane >> 5) & 1, c4 = ((lane >> 4) & 1) * 4;
    const int yo = y0 + 2 * wid + py;
    float* obase = outn + ((size_t)(w * 24 + xx) * 24 + yo) * 24;
#pragma unroll
    for (int m = 0; m < 3; ++m) {
        float o[4];
#pragma unroll
        for (int r = 0; r < 4; ++r) {
            float mine = acc[m][r];
            float oth = __shfl_xor(mine, 1);
            o[r] = fmaxf(mine + bv, 0.f) + fmaxf(oth + bv, 0.f);
        }
        if (col == 0)
            *(float4*)(obase + m * 8 + c4) = make_float4(o[0], o[1], o[2], o[3]);
    }
}

extern "C" void kernel_launch(void* const* d_in, const int* in_sizes, int n_in,
                              void* d_out, int out_size, void* d_ws, size_t ws_size,
                              hipStream_t stream) {
    const float* x  = (const float*)d_in[0];
    const float* w1 = (const float*)d_in[1];
    const float* b1 = (const float*)d_in[2];
    const float* w2 = (const float*)d_in[3];
    const float* b2 = (const float*)d_in[4];
    const float* w3 = (const float*)d_in[5];
    const float* b3 = (const float*)d_in[6];
    float* out = (float*)d_out;
    char* ws = (char*)d_ws;
    if (ws_size < WS_NEED) return;

    float*  Wp1  = (float*)(ws + WP1_OFF);
    ushort* Wp3c = (ushort*)(ws + WP3C_OFF);
    ushort* Wp2f = (ushort*)(ws + WP2F_OFF);
    char* bufbase = ws + BUF_OFF;

    // ws-adaptive batch width (deterministic: depends only on ws_size)
    int NB = (int)((ws_size - BUF_OFF) / PER_N);
    if (NB > 8) NB = 8;
    if (NB < 1) return;
    const int nchunks = (8 + NB - 1) / NB;
    const int base = 8 / nchunks, rem = 8 % nchunks;

    prep_weights<<<191, 256, 0, stream>>>(w1, w2, w3, Wp1, Wp3c, Wp2f);
    halo_zero<<<NB * 576, 256, 0, stream>>>(bufbase);

    int c = 0;
    for (int k = 0; k < nchunks; ++k) {
        const int nb = base + (k < rem ? 1 : 0);
        conv1_plane2<<<nb * 576, 576, 0, stream>>>(
            x + (size_t)c * S4, Wp1, b1, bufbase);
        conv2_mfma<<<nb * 3456, 256, 0, stream>>>(
            bufbase, (const char*)Wp2f, b2);
        conv3_mfma<<<nb * 1728, 256, 0, stream>>>(
            bufbase, (const char*)Wp3c, b3, out + (size_t)c * S4);
        c += nb;
    }
}